// Round 2
// baseline (1893.519 us; speedup 1.0000x reference)
//
#include <hip/hip_runtime.h>

#define N_NODES 200000
#define N_EDGES 800000
#define N_RULES 50000
#define NLAYERS 24
#define SCAN_NB 196        // ceil(200000/1024)
#define RP_STRIDE 200064   // ints per rp array (padded)

typedef short bf16x8 __attribute__((ext_vector_type(8)));
typedef float floatx4 __attribute__((ext_vector_type(4)));
typedef unsigned short ushort4v __attribute__((ext_vector_type(4)));

__device__ __forceinline__ unsigned short f2bf(float f) {
  unsigned int b = __float_as_uint(f);
  b += 0x7FFFu + ((b >> 16) & 1u);          // round-to-nearest-even
  return (unsigned short)(b >> 16);
}
__device__ __forceinline__ float bf2f(unsigned short u) {
  return __uint_as_float(((unsigned int)u) << 16);
}

// ---------------- CSR build (unpadded; rank captured in hist) ----------------

__global__ void k_hist(const int* __restrict__ src, const int* __restrict__ tgt,
                       int* __restrict__ deg_out, int* __restrict__ deg_back,
                       int* __restrict__ rank_out, int* __restrict__ rank_back) {
  int e = blockIdx.x * 256 + threadIdx.x;   // E = 3125*256 exact
  rank_out[e]  = atomicAdd(&deg_out[tgt[e]], 1);   // rank = old count
  rank_back[e] = atomicAdd(&deg_back[src[e]], 1);
}

__global__ void k_scanA(const int* __restrict__ deg, int* __restrict__ part) {
  int y = blockIdx.y;
  const int* d = deg + y * N_NODES;
  __shared__ int sh[256];
  int t = threadIdx.x;
  int base = blockIdx.x * 1024 + t * 4;
  int s = 0;
  #pragma unroll
  for (int k = 0; k < 4; ++k) { int i = base + k; if (i < N_NODES) s += d[i]; }
  sh[t] = s; __syncthreads();
  for (int off = 128; off > 0; off >>= 1) { if (t < off) sh[t] += sh[t + off]; __syncthreads(); }
  if (t == 0) part[y * SCAN_NB + blockIdx.x] = sh[0];
}

__global__ void k_scanB(int* __restrict__ part, int* __restrict__ rp) {
  int y = blockIdx.y;
  __shared__ int buf[256];
  int t = threadIdx.x;
  int v = (t < SCAN_NB) ? part[y * SCAN_NB + t] : 0;
  buf[t] = v; __syncthreads();
  for (int off = 1; off < 256; off <<= 1) {
    int x = (t >= off) ? buf[t - off] : 0;
    __syncthreads();
    buf[t] += x;
    __syncthreads();
  }
  if (t < SCAN_NB) part[y * SCAN_NB + t] = buf[t] - v;   // exclusive
  if (t == 0) rp[y * RP_STRIDE + N_NODES] = N_EDGES;
}

__global__ void k_scanC(const int* __restrict__ deg, const int* __restrict__ part,
                        int* __restrict__ rp) {
  int y = blockIdx.y;
  const int* d = deg + y * N_NODES;
  int* r = rp + y * RP_STRIDE;
  __shared__ int buf[256];
  int t = threadIdx.x;
  int base = blockIdx.x * 1024 + t * 4;
  int dv[4]; int s = 0;
  #pragma unroll
  for (int k = 0; k < 4; ++k) { int i = base + k; dv[k] = (i < N_NODES) ? d[i] : 0; s += dv[k]; }
  buf[t] = s; __syncthreads();
  int sv = s;
  for (int off = 1; off < 256; off <<= 1) {
    int x = (t >= off) ? buf[t - off] : 0;
    __syncthreads();
    buf[t] += x;
    __syncthreads();
  }
  int e = part[y * SCAN_NB + blockIdx.x] + buf[t] - sv;
  #pragma unroll
  for (int k = 0; k < 4; ++k) { int i = base + k; if (i < N_NODES) r[i] = e; e += dv[k]; }
}

// atomic-free fill: slot = rp[node] + rank[e]
__global__ void k_fill(const int* __restrict__ src, const int* __restrict__ tgt,
                       const int* __restrict__ rp_out, const int* __restrict__ rp_back,
                       const int* __restrict__ rank_out, const int* __restrict__ rank_back,
                       int* __restrict__ ci_out, int* __restrict__ ci_back) {
  int e = blockIdx.x * 256 + threadIdx.x;
  int s = src[e], t = tgt[e];
  ci_out[rp_out[t] + rank_out[e]] = s;
  ci_back[rp_back[s] + rank_back[e]] = t;
}

// ---------------- BN-folded weight prep (bf16 MFMA A-fragments) ----------------
__global__ void k_prep(const float* __restrict__ W, const float* __restrict__ b,
                       const float* __restrict__ gamma, const float* __restrict__ beta,
                       const float* __restrict__ rmean, const float* __restrict__ rvar,
                       unsigned short* __restrict__ WpF, float* __restrict__ bp) {
  int d = blockIdx.x, l = blockIdx.y, lane = threadIdx.x;
  int ld = l * 2 + d;
  __shared__ float s_s[64], t_s[64];
  float s = gamma[ld * 64 + lane] * rsqrtf(rvar[ld * 64 + lane] + 1e-5f);
  s_s[lane] = s;
  t_s[lane] = beta[ld * 64 + lane] - rmean[ld * 64 + lane] * s;
  __syncthreads();
  float bias = b[ld * 64 + lane];
  for (int j = 0; j < 64; ++j) bias += W[(ld * 64 + lane) * 64 + j] * t_s[j];
  bp[ld * 64 + lane] = bias;
  #pragma unroll
  for (int f = 0; f < 8; ++f) {
    int ct = f >> 1, kh = f & 1;
    int row = ct * 16 + (lane & 15);
    #pragma unroll
    for (int jj = 0; jj < 8; ++jj) {
      int k = kh * 32 + (lane >> 4) * 8 + jj;
      float val = W[(ld * 64 + row) * 64 + k] * s_s[k];
      WpF[(ld * 8 + f) * 512 + lane * 8 + jj] = f2bf(val);
    }
  }
}

// ---------------- Wh prep: split bf16 hi/lo MFMA A-fragments ----------------
__global__ void k_prep2(const float* __restrict__ Wh,
                        unsigned short* __restrict__ WhFhi,
                        unsigned short* __restrict__ WhFlo) {
  int jt = blockIdx.x, lane = threadIdx.x;
  #pragma unroll
  for (int kh = 0; kh < 2; ++kh) {
    #pragma unroll
    for (int jj = 0; jj < 8; ++jj) {
      int j = jt * 16 + (lane & 15);
      int k = kh * 32 + (lane >> 4) * 8 + jj;
      float wv = Wh[j * 64 + k];
      unsigned short hi = f2bf(wv);
      WhFhi[(jt * 2 + kh) * 512 + lane * 8 + jj] = hi;
      WhFlo[(jt * 2 + kh) * 512 + lane * 8 + jj] = f2bf(wv - bf2f(hi));
    }
  }
}

// ---------------- embedding gather (bf16 hi/lo master) ----------------
__global__ void k_embed(const int* __restrict__ nodes, const float* __restrict__ emb,
                        unsigned short* __restrict__ hi_a,
                        unsigned short* __restrict__ lo) {
  int gid = blockIdx.x * 256 + threadIdx.x;     // N*64 = 50000*256 exact
  int i = gid >> 6, c = gid & 63;
  float v = emb[nodes[i] * 64 + c];
  unsigned short h = f2bf(v);
  hi_a[gid] = h;
  lo[gid] = f2bf(v - bf2f(h));
}

// ---------------- fused layer (round-11 structure) --------------------------
// vs round-10: (a) y_s transpose buffer ELIMINATED — both directions' means are
//   gathered into a doubled per-warp m_s first, then both MFMAs run
//   back-to-back and the epilogue is fused per-ct in MFMA D-layout (ushort4
//   8B ops). LDS 27.1KB -> 18.9KB => 8 blocks/CU (32-wave cap, was 24).
//   (b) round-9 proven inner gather loop (16 in flight) + register-resident rp.
//   (c) __launch_bounds__(256,8) pins VGPR<=64 for the 8-wave/SIMD tier.
__global__ __launch_bounds__(256, 8) void k_layer(
    const unsigned short* __restrict__ hi_in,      // gather source + master hi
    unsigned short* __restrict__ hi_out,
    unsigned short* __restrict__ lo,               // master lo (in-place)
    const int* __restrict__ rp0, const int* __restrict__ ci0,
    const int* __restrict__ rp1, const int* __restrict__ ci1,
    const unsigned short* __restrict__ WfL, const float* __restrict__ bpL) {
  __shared__ __align__(16) unsigned short m_s[2][4][16 * 72];  // [dir][warp], bf16, pitch 72
  __shared__ float bp_s[128];
  int tid = threadIdx.x, lane = tid & 63, w = tid >> 6;
  if (tid < 128) bp_s[tid] = bpL[tid];
  __syncthreads();
  int base = (blockIdx.x * 4 + w) * 16;
  int n15 = lane & 15, q = lane >> 4;

  // rp for BOTH dirs into registers; first ci chunk of BOTH dirs in flight now
  int rpv0 = (lane < 17) ? rp0[base + lane] : 0;
  int rpv1 = (lane < 17) ? rp1[base + lane] : 0;
  int rs0 = __builtin_amdgcn_readlane(rpv0, 0);
  int re0 = __builtin_amdgcn_readlane(rpv0, 16);
  int rs1 = __builtin_amdgcn_readlane(rpv1, 0);
  int re1 = __builtin_amdgcn_readlane(rpv1, 16);
  int cv0 = (rs0 + lane < re0) ? ci0[rs0 + lane] : 0;
  int cv1 = (rs1 + lane < re1) ? ci1[rs1 + lane] : 0;

  // -------- gather passes: both directions into m_s[d][w] --------
  for (int d = 0; d < 2; ++d) {
    const int* ci = d ? ci1 : ci0;
    int rpv = d ? rpv1 : rpv0;
    int rs  = d ? rs1  : rs0;
    int re  = d ? re1  : re0;
    int cv  = d ? cv1  : cv0;
    unsigned short* md = &m_s[d][w][0];
    int cur = 0;
    int cstart = rs;
    int cend = __builtin_amdgcn_readlane(rpv, 1);
    float acc = 0.f;

    for (int cb = rs; cb < re; cb += 64) {
      int ce = (cb + 64 < re) ? cb + 64 : re;
      // double-buffer: next 64-edge index block load in flight
      int cv_next = (cb + 64 + lane < re) ? ci[cb + 64 + lane] : 0;
      for (int j0 = cb; j0 < ce; j0 += 16) {
        float v[16];                                   // 16 UNCONDITIONAL gathers in flight
        #pragma unroll
        for (int u = 0; u < 16; ++u) {
          int sn = __builtin_amdgcn_readlane(cv, j0 + u - cb);  // OOB lanes hold 0 -> safe row
          v[u] = bf2f(hi_in[sn * 64 + lane]);
        }
        #pragma unroll
        for (int u = 0; u < 16; ++u) {
          int j = j0 + u;
          if (j < ce) {                                // guard ACCUMULATION only
            while (j >= cend) {                        // flush node `cur`
              int deg = cend - cstart;
              float invc = deg > 0 ? __builtin_amdgcn_rcpf((float)deg) : 0.f;
              md[cur * 72 + lane] = f2bf(acc * invc);
              acc = 0.f; cur++; cstart = cend;
              cend = __builtin_amdgcn_readlane(rpv, cur + 1);
            }
            acc += v[u];
          }
        }
      }
      cv = cv_next;
    }
    #pragma unroll 1
    while (cur < 16) {                                 // trailing flush
      int deg = cend - cstart;
      float invc = deg > 0 ? __builtin_amdgcn_rcpf((float)deg) : 0.f;
      md[cur * 72 + lane] = f2bf(acc * invc);
      acc = 0.f; cstart = cend; cur++;
      if (cur < 16) cend = __builtin_amdgcn_readlane(rpv, cur + 1);
    }
  }

  // -------- MFMA both dirs + fused ReLU/combine/residual epilogue --------
  bf16x8 b0d0 = *(const bf16x8*)&m_s[0][w][n15 * 72 + q * 8];
  bf16x8 b1d0 = *(const bf16x8*)&m_s[0][w][n15 * 72 + 32 + q * 8];
  bf16x8 b0d1 = *(const bf16x8*)&m_s[1][w][n15 * 72 + q * 8];
  bf16x8 b1d1 = *(const bf16x8*)&m_s[1][w][n15 * 72 + 32 + q * 8];
  #pragma unroll
  for (int ct = 0; ct < 4; ++ct) {
    const unsigned short* wf0 = WfL + (ct * 2) * 512 + lane * 8;        // d0 frags
    const unsigned short* wf1 = WfL + 4096 + (ct * 2) * 512 + lane * 8; // d1 frags
    floatx4 d40 = {0.f, 0.f, 0.f, 0.f};
    floatx4 d41 = {0.f, 0.f, 0.f, 0.f};
    d40 = __builtin_amdgcn_mfma_f32_16x16x32_bf16(*(const bf16x8*)wf0, b0d0, d40, 0, 0, 0);
    d40 = __builtin_amdgcn_mfma_f32_16x16x32_bf16(*(const bf16x8*)(wf0 + 512), b1d0, d40, 0, 0, 0);
    d41 = __builtin_amdgcn_mfma_f32_16x16x32_bf16(*(const bf16x8*)wf1, b0d1, d41, 0, 0, 0);
    d41 = __builtin_amdgcn_mfma_f32_16x16x32_bf16(*(const bf16x8*)(wf1 + 512), b1d1, d41, 0, 0, 0);
    // D: col = n15 = node, row = ct*16 + q*4 + i = channel
    int c0 = ct * 16 + q * 4;
    int gi = (base + n15) * 64 + c0;                   // element index, 8B aligned
    ushort4v hv = *(const ushort4v*)&hi_in[gi];
    ushort4v lv = *(const ushort4v*)&lo[gi];
    ushort4v ho, lno;
    #pragma unroll
    for (int i = 0; i < 4; ++i) {
      float yv = fmaxf(d40[i] + bp_s[c0 + i], 0.f)
               + fmaxf(d41[i] + bp_s[64 + c0 + i], 0.f);
      float xv = bf2f(hv[i]) + bf2f(lv[i]) + yv;
      unsigned short h = f2bf(xv);
      ho[i] = h;
      lno[i] = f2bf(xv - bf2f(h));
    }
    *(ushort4v*)&hi_out[gi] = ho;
    *(ushort4v*)&lo[gi] = lno;                          // in-place: rows owned by this warp
  }
}

// ---------------- readout (MFMA; hi/lo split comes free from master format) ----
__global__ __launch_bounds__(256) void k_final(
    const unsigned short* __restrict__ hi, const unsigned short* __restrict__ lo,
    const int* __restrict__ rules,
    const unsigned short* __restrict__ WhFhi, const unsigned short* __restrict__ WhFlo,
    const float* __restrict__ bh, const float* __restrict__ Wo,
    float* __restrict__ out) {
  __shared__ __align__(16) float bh_s[1024], wo_s[1024];
  int tid = threadIdx.x, lane = tid & 63, w = tid >> 6;
  ((floatx4*)bh_s)[tid] = ((const floatx4*)bh)[tid];
  ((floatx4*)wo_s)[tid] = ((const floatx4*)Wo)[tid];
  __syncthreads();
  int n15 = lane & 15, q = lane >> 4;
  int rbase = (blockIdx.x * 4 + w) * 16;
  int ru = rbase + n15;
  int nd = rules[ru < N_RULES ? ru : N_RULES - 1];
  bf16x8 b0h = *(const bf16x8*)&hi[nd * 64 + q * 8];
  bf16x8 b1h = *(const bf16x8*)&hi[nd * 64 + 32 + q * 8];
  bf16x8 b0l = *(const bf16x8*)&lo[nd * 64 + q * 8];
  bf16x8 b1l = *(const bf16x8*)&lo[nd * 64 + 32 + q * 8];
  float acc = 0.f;
  #pragma unroll 4
  for (int jt = 0; jt < 64; ++jt) {
    const unsigned short* fh = WhFhi + (jt * 2) * 512 + lane * 8;
    const unsigned short* fl = WhFlo + (jt * 2) * 512 + lane * 8;
    bf16x8 a0h = *(const bf16x8*)fh;
    bf16x8 a1h = *(const bf16x8*)(fh + 512);
    bf16x8 a0l = *(const bf16x8*)fl;
    bf16x8 a1l = *(const bf16x8*)(fl + 512);
    floatx4 d4 = {0.f, 0.f, 0.f, 0.f};
    d4 = __builtin_amdgcn_mfma_f32_16x16x32_bf16(a0h, b0h, d4, 0, 0, 0);
    d4 = __builtin_amdgcn_mfma_f32_16x16x32_bf16(a1h, b1h, d4, 0, 0, 0);
    d4 = __builtin_amdgcn_mfma_f32_16x16x32_bf16(a0h, b0l, d4, 0, 0, 0);
    d4 = __builtin_amdgcn_mfma_f32_16x16x32_bf16(a1h, b1l, d4, 0, 0, 0);
    d4 = __builtin_amdgcn_mfma_f32_16x16x32_bf16(a0l, b0h, d4, 0, 0, 0);
    d4 = __builtin_amdgcn_mfma_f32_16x16x32_bf16(a1l, b1h, d4, 0, 0, 0);
    floatx4 bh4 = *(const floatx4*)&bh_s[jt * 16 + q * 4];
    floatx4 wo4 = *(const floatx4*)&wo_s[jt * 16 + q * 4];
    #pragma unroll
    for (int i = 0; i < 4; ++i)
      acc += fmaxf(d4[i] + bh4[i], 0.f) * wo4[i];
  }
  acc += __shfl_down(acc, 32);     // fold q2,q3 into q0,q1
  acc += __shfl_down(acc, 16);     // fold q1 into q0
  if (lane < 16 && rbase + lane < N_RULES) out[rbase + lane] = acc;
}

// ---------------- launch ----------------
extern "C" void kernel_launch(void* const* d_in, const int* in_sizes, int n_in,
                              void* d_out, int out_size, void* d_ws, size_t ws_size,
                              hipStream_t stream) {
  const int* nodes = (const int*)d_in[0];
  const int* sources = (const int*)d_in[1];
  const int* targets = (const int*)d_in[2];
  const int* rules = (const int*)d_in[3];
  const float* emb = (const float*)d_in[4];
  const float* W = (const float*)d_in[5];
  const float* b = (const float*)d_in[6];
  const float* gamma = (const float*)d_in[7];
  const float* beta = (const float*)d_in[8];
  const float* rmean = (const float*)d_in[9];
  const float* rvar = (const float*)d_in[10];
  const float* Wh = (const float*)d_in[11];
  const float* bh = (const float*)d_in[12];
  const float* Wo = (const float*)d_in[13];
  float* out = (float*)d_out;

  if (ws_size < 95100000u) return;  // need ~95.1 MB scratch

  char* ws = (char*)d_ws;
  unsigned short* hi_a = (unsigned short*)(ws + 0);          // 25.6 MB
  unsigned short* hi_b = (unsigned short*)(ws + 25600000);   // 25.6 MB
  unsigned short* lo   = (unsigned short*)(ws + 51200000);   // 25.6 MB
  int* deg_out  = (int*)(ws + 76800000);                     // 800 KB
  int* deg_back = (int*)(ws + 77600000);                     // 800 KB
  int* rank_out = (int*)(ws + 78400000);                     // 3.2 MB
  int* rank_back= (int*)(ws + 81600000);                     // 3.2 MB
  int* rp_out   = (int*)(ws + 84800000);                     // RP_STRIDE ints
  int* rp_back  = (int*)(ws + 85600256);
  int* ci_out   = (int*)(ws + 86400512);                     // 3.2 MB
  int* ci_back  = (int*)(ws + 89600512);                     // 3.2 MB
  int* part     = (int*)(ws + 92800512);                     // 1568 B
  unsigned short* WpF   = (unsigned short*)(ws + 92802080);  // 384 KB (16B aligned)
  float* bp             = (float*)(ws + 93195296);           // 12 KB
  unsigned short* WhFhi = (unsigned short*)(ws + 93207584);  // 128 KB
  unsigned short* WhFlo = (unsigned short*)(ws + 93338656);  // 128 KB -> ends 93,469,728

  // zero deg_out/deg_back (contiguous 1.6 MB)
  (void)hipMemsetAsync(deg_out, 0, 1600000u, stream);

  k_hist<<<3125, 256, 0, stream>>>(sources, targets, deg_out, deg_back,
                                   rank_out, rank_back);
  k_scanA<<<dim3(SCAN_NB, 2), 256, 0, stream>>>(deg_out, part);
  k_scanB<<<dim3(1, 2), 256, 0, stream>>>(part, rp_out);
  k_scanC<<<dim3(SCAN_NB, 2), 256, 0, stream>>>(deg_out, part, rp_out);
  k_fill<<<3125, 256, 0, stream>>>(sources, targets, rp_out, rp_back,
                                   rank_out, rank_back, ci_out, ci_back);
  k_prep<<<dim3(2, NLAYERS), 64, 0, stream>>>(W, b, gamma, beta, rmean, rvar, WpF, bp);
  k_prep2<<<64, 64, 0, stream>>>(Wh, WhFhi, WhFlo);
  k_embed<<<50000, 256, 0, stream>>>(nodes, emb, hi_a, lo);

  const unsigned short* hin = hi_a;
  unsigned short* hout = hi_b;
  for (int l = 0; l < NLAYERS; ++l) {
    k_layer<<<3125, 256, 0, stream>>>(hin, hout, lo,
                                      rp_out, ci_out, rp_back, ci_back,
                                      WpF + (size_t)l * 8192, bp + (size_t)l * 128);
    const unsigned short* tmp = hin; hin = hout; hout = (unsigned short*)tmp;
  }
  k_final<<<782, 256, 0, stream>>>(hin, lo, rules, WhFhi, WhFlo, bh, Wo, out);
}

// Round 3
// 1822.413 us; speedup vs baseline: 1.0390x; 1.0390x over previous
//
#include <hip/hip_runtime.h>

#define N_NODES 200000
#define N_EDGES 800000
#define N_RULES 50000
#define NLAYERS 24
#define SCAN_NB 196        // ceil(200000/1024)
#define RP_STRIDE 200064   // ints per rp array (padded)

typedef short bf16x8 __attribute__((ext_vector_type(8)));
typedef float floatx4 __attribute__((ext_vector_type(4)));

__device__ __forceinline__ unsigned short f2bf(float f) {
  unsigned int b = __float_as_uint(f);
  b += 0x7FFFu + ((b >> 16) & 1u);          // round-to-nearest-even
  return (unsigned short)(b >> 16);
}
__device__ __forceinline__ float bf2f(unsigned short u) {
  return __uint_as_float(((unsigned int)u) << 16);
}

// ---------------- CSR build (unpadded; rank captured in hist) ----------------

__global__ void k_hist(const int* __restrict__ src, const int* __restrict__ tgt,
                       int* __restrict__ deg_out, int* __restrict__ deg_back,
                       int* __restrict__ rank_out, int* __restrict__ rank_back) {
  int e = blockIdx.x * 256 + threadIdx.x;   // E = 3125*256 exact
  rank_out[e]  = atomicAdd(&deg_out[tgt[e]], 1);   // rank = old count
  rank_back[e] = atomicAdd(&deg_back[src[e]], 1);
}

__global__ void k_scanA(const int* __restrict__ deg, int* __restrict__ part) {
  int y = blockIdx.y;
  const int* d = deg + y * N_NODES;
  __shared__ int sh[256];
  int t = threadIdx.x;
  int base = blockIdx.x * 1024 + t * 4;
  int s = 0;
  #pragma unroll
  for (int k = 0; k < 4; ++k) { int i = base + k; if (i < N_NODES) s += d[i]; }
  sh[t] = s; __syncthreads();
  for (int off = 128; off > 0; off >>= 1) { if (t < off) sh[t] += sh[t + off]; __syncthreads(); }
  if (t == 0) part[y * SCAN_NB + blockIdx.x] = sh[0];
}

__global__ void k_scanB(int* __restrict__ part, int* __restrict__ rp) {
  int y = blockIdx.y;
  __shared__ int buf[256];
  int t = threadIdx.x;
  int v = (t < SCAN_NB) ? part[y * SCAN_NB + t] : 0;
  buf[t] = v; __syncthreads();
  for (int off = 1; off < 256; off <<= 1) {
    int x = (t >= off) ? buf[t - off] : 0;
    __syncthreads();
    buf[t] += x;
    __syncthreads();
  }
  if (t < SCAN_NB) part[y * SCAN_NB + t] = buf[t] - v;   // exclusive
  if (t == 0) rp[y * RP_STRIDE + N_NODES] = N_EDGES;
}

__global__ void k_scanC(const int* __restrict__ deg, const int* __restrict__ part,
                        int* __restrict__ rp) {
  int y = blockIdx.y;
  const int* d = deg + y * N_NODES;
  int* r = rp + y * RP_STRIDE;
  __shared__ int buf[256];
  int t = threadIdx.x;
  int base = blockIdx.x * 1024 + t * 4;
  int dv[4]; int s = 0;
  #pragma unroll
  for (int k = 0; k < 4; ++k) { int i = base + k; dv[k] = (i < N_NODES) ? d[i] : 0; s += dv[k]; }
  buf[t] = s; __syncthreads();
  int sv = s;
  for (int off = 1; off < 256; off <<= 1) {
    int x = (t >= off) ? buf[t - off] : 0;
    __syncthreads();
    buf[t] += x;
    __syncthreads();
  }
  int e = part[y * SCAN_NB + blockIdx.x] + buf[t] - sv;
  #pragma unroll
  for (int k = 0; k < 4; ++k) { int i = base + k; if (i < N_NODES) r[i] = e; e += dv[k]; }
}

// atomic-free fill: slot = rp[node] + rank[e]
__global__ void k_fill(const int* __restrict__ src, const int* __restrict__ tgt,
                       const int* __restrict__ rp_out, const int* __restrict__ rp_back,
                       const int* __restrict__ rank_out, const int* __restrict__ rank_back,
                       int* __restrict__ ci_out, int* __restrict__ ci_back) {
  int e = blockIdx.x * 256 + threadIdx.x;
  int s = src[e], t = tgt[e];
  ci_out[rp_out[t] + rank_out[e]] = s;
  ci_back[rp_back[s] + rank_back[e]] = t;
}

// ---------------- BN-folded weight prep (bf16 MFMA A-fragments) ----------------
__global__ void k_prep(const float* __restrict__ W, const float* __restrict__ b,
                       const float* __restrict__ gamma, const float* __restrict__ beta,
                       const float* __restrict__ rmean, const float* __restrict__ rvar,
                       unsigned short* __restrict__ WpF, float* __restrict__ bp) {
  int d = blockIdx.x, l = blockIdx.y, lane = threadIdx.x;
  int ld = l * 2 + d;
  __shared__ float s_s[64], t_s[64];
  float s = gamma[ld * 64 + lane] * rsqrtf(rvar[ld * 64 + lane] + 1e-5f);
  s_s[lane] = s;
  t_s[lane] = beta[ld * 64 + lane] - rmean[ld * 64 + lane] * s;
  __syncthreads();
  float bias = b[ld * 64 + lane];
  for (int j = 0; j < 64; ++j) bias += W[(ld * 64 + lane) * 64 + j] * t_s[j];
  bp[ld * 64 + lane] = bias;
  #pragma unroll
  for (int f = 0; f < 8; ++f) {
    int ct = f >> 1, kh = f & 1;
    int row = ct * 16 + (lane & 15);
    #pragma unroll
    for (int jj = 0; jj < 8; ++jj) {
      int k = kh * 32 + (lane >> 4) * 8 + jj;
      float val = W[(ld * 64 + row) * 64 + k] * s_s[k];
      WpF[(ld * 8 + f) * 512 + lane * 8 + jj] = f2bf(val);
    }
  }
}

// ---------------- Wh prep: split bf16 hi/lo MFMA A-fragments ----------------
__global__ void k_prep2(const float* __restrict__ Wh,
                        unsigned short* __restrict__ WhFhi,
                        unsigned short* __restrict__ WhFlo) {
  int jt = blockIdx.x, lane = threadIdx.x;
  #pragma unroll
  for (int kh = 0; kh < 2; ++kh) {
    #pragma unroll
    for (int jj = 0; jj < 8; ++jj) {
      int j = jt * 16 + (lane & 15);
      int k = kh * 32 + (lane >> 4) * 8 + jj;
      float wv = Wh[j * 64 + k];
      unsigned short hi = f2bf(wv);
      WhFhi[(jt * 2 + kh) * 512 + lane * 8 + jj] = hi;
      WhFlo[(jt * 2 + kh) * 512 + lane * 8 + jj] = f2bf(wv - bf2f(hi));
    }
  }
}

// ---------------- embedding gather (bf16 hi/lo master) ----------------
__global__ void k_embed(const int* __restrict__ nodes, const float* __restrict__ emb,
                        unsigned short* __restrict__ hi_a,
                        unsigned short* __restrict__ lo) {
  int gid = blockIdx.x * 256 + threadIdx.x;     // N*64 = 50000*256 exact
  int i = gid >> 6, c = gid & 63;
  float v = emb[nodes[i] * 64 + c];
  unsigned short h = f2bf(v);
  hi_a[gid] = h;
  lo[gid] = f2bf(v - bf2f(h));
}

// ---------------- fused layer (round-12 structure) --------------------------
// round-11 occupancy (LDS 18944 -> 8 blocks/CU) + round-9 coalesced epilogue.
// The f32 y-transpose tile lives in the SAME LDS bytes as m_s: after the
// B-fragments are loaded to registers, the warp's m_s region (4608 B) is dead
// and is reused as the 4352 B y tile (warp-private -> no sync; read-before-
// write enforced by data dependence + alias analysis).
__global__ __launch_bounds__(256, 8) void k_layer(
    const unsigned short* __restrict__ hi_in,      // gather source + master hi
    unsigned short* __restrict__ hi_out,
    unsigned short* __restrict__ lo,               // master lo (in-place)
    const int* __restrict__ rp0, const int* __restrict__ ci0,
    const int* __restrict__ rp1, const int* __restrict__ ci1,
    const unsigned short* __restrict__ WfL, const float* __restrict__ bpL) {
  __shared__ __align__(16) unsigned short m_s[4][2][16 * 72];  // [warp][dir], bf16, pitch 72
  __shared__ float bp_s[128];
  int tid = threadIdx.x, lane = tid & 63, w = tid >> 6;
  if (tid < 128) bp_s[tid] = bpL[tid];
  __syncthreads();
  int base = (blockIdx.x * 4 + w) * 16;
  int n15 = lane & 15, q = lane >> 4;

  // rp for BOTH dirs into registers; first ci chunk of BOTH dirs in flight now
  int rpv0 = (lane < 17) ? rp0[base + lane] : 0;
  int rpv1 = (lane < 17) ? rp1[base + lane] : 0;
  int rs0 = __builtin_amdgcn_readlane(rpv0, 0);
  int re0 = __builtin_amdgcn_readlane(rpv0, 16);
  int rs1 = __builtin_amdgcn_readlane(rpv1, 0);
  int re1 = __builtin_amdgcn_readlane(rpv1, 16);
  int cv0 = (rs0 + lane < re0) ? ci0[rs0 + lane] : 0;
  int cv1 = (rs1 + lane < re1) ? ci1[rs1 + lane] : 0;

  // -------- gather passes: both directions into m_s[w][d] --------
  for (int d = 0; d < 2; ++d) {
    const int* ci = d ? ci1 : ci0;
    int rpv = d ? rpv1 : rpv0;
    int rs  = d ? rs1  : rs0;
    int re  = d ? re1  : re0;
    int cv  = d ? cv1  : cv0;
    unsigned short* md = &m_s[w][d][0];
    int cur = 0;
    int cstart = rs;
    int cend = __builtin_amdgcn_readlane(rpv, 1);
    float acc = 0.f;

    for (int cb = rs; cb < re; cb += 64) {
      int ce = (cb + 64 < re) ? cb + 64 : re;
      // double-buffer: next 64-edge index block load in flight
      int cv_next = (cb + 64 + lane < re) ? ci[cb + 64 + lane] : 0;
      for (int j0 = cb; j0 < ce; j0 += 16) {
        float v[16];                                   // 16 UNCONDITIONAL gathers in flight
        #pragma unroll
        for (int u = 0; u < 16; ++u) {
          int sn = __builtin_amdgcn_readlane(cv, j0 + u - cb);  // OOB lanes hold 0 -> safe row
          v[u] = bf2f(hi_in[sn * 64 + lane]);
        }
        #pragma unroll
        for (int u = 0; u < 16; ++u) {
          int j = j0 + u;
          if (j < ce) {                                // guard ACCUMULATION only
            while (j >= cend) {                        // flush node `cur`
              int deg = cend - cstart;
              float invc = deg > 0 ? __builtin_amdgcn_rcpf((float)deg) : 0.f;
              md[cur * 72 + lane] = f2bf(acc * invc);
              acc = 0.f; cur++; cstart = cend;
              cend = __builtin_amdgcn_readlane(rpv, cur + 1);
            }
            acc += v[u];
          }
        }
      }
      cv = cv_next;
    }
    #pragma unroll 1
    while (cur < 16) {                                 // trailing flush
      int deg = cend - cstart;
      float invc = deg > 0 ? __builtin_amdgcn_rcpf((float)deg) : 0.f;
      md[cur * 72 + lane] = f2bf(acc * invc);
      acc = 0.f; cstart = cend; cur++;
      if (cur < 16) cend = __builtin_amdgcn_readlane(rpv, cur + 1);
    }
  }

  // -------- MFMA both dirs; y into warp-private LDS scratch (reuses m_s) ----
  bf16x8 b0d0 = *(const bf16x8*)&m_s[w][0][n15 * 72 + q * 8];
  bf16x8 b1d0 = *(const bf16x8*)&m_s[w][0][n15 * 72 + 32 + q * 8];
  bf16x8 b0d1 = *(const bf16x8*)&m_s[w][1][n15 * 72 + q * 8];
  bf16x8 b1d1 = *(const bf16x8*)&m_s[w][1][n15 * 72 + 32 + q * 8];
  float* ys = (float*)&m_s[w][0][0];                   // 4352 B <= 4608 B region
  #pragma unroll
  for (int ct = 0; ct < 4; ++ct) {
    const unsigned short* wf0 = WfL + (ct * 2) * 512 + lane * 8;        // d0 frags
    const unsigned short* wf1 = WfL + 4096 + (ct * 2) * 512 + lane * 8; // d1 frags
    floatx4 d40 = {0.f, 0.f, 0.f, 0.f};
    floatx4 d41 = {0.f, 0.f, 0.f, 0.f};
    d40 = __builtin_amdgcn_mfma_f32_16x16x32_bf16(*(const bf16x8*)wf0, b0d0, d40, 0, 0, 0);
    d40 = __builtin_amdgcn_mfma_f32_16x16x32_bf16(*(const bf16x8*)(wf0 + 512), b1d0, d40, 0, 0, 0);
    d41 = __builtin_amdgcn_mfma_f32_16x16x32_bf16(*(const bf16x8*)wf1, b0d1, d41, 0, 0, 0);
    d41 = __builtin_amdgcn_mfma_f32_16x16x32_bf16(*(const bf16x8*)(wf1 + 512), b1d1, d41, 0, 0, 0);
    // D: col = n15 = node, row = ct*16 + q*4 + i = channel
    int c0 = ct * 16 + q * 4;
    floatx4 yv;
    #pragma unroll
    for (int i = 0; i < 4; ++i)
      yv[i] = fmaxf(d40[i] + bp_s[c0 + i], 0.f)
            + fmaxf(d41[i] + bp_s[64 + c0 + i], 0.f);
    *(floatx4*)&ys[n15 * 68 + c0] = yv;                // pitch 68 f32
  }

  // epilogue: row-major coalesced; residual on hi/lo, re-split, store
  #pragma unroll
  for (int r = 0; r < 16; ++r) {
    int gi = (base + r) * 64 + lane;
    float xv = bf2f(hi_in[gi]) + bf2f(lo[gi]) + ys[r * 68 + lane];
    unsigned short h = f2bf(xv);
    hi_out[gi] = h;
    lo[gi] = f2bf(xv - bf2f(h));   // in-place: only this warp touches these rows
  }
}

// ---------------- readout (MFMA; hi/lo split comes free from master format) ----
__global__ __launch_bounds__(256) void k_final(
    const unsigned short* __restrict__ hi, const unsigned short* __restrict__ lo,
    const int* __restrict__ rules,
    const unsigned short* __restrict__ WhFhi, const unsigned short* __restrict__ WhFlo,
    const float* __restrict__ bh, const float* __restrict__ Wo,
    float* __restrict__ out) {
  __shared__ __align__(16) float bh_s[1024], wo_s[1024];
  int tid = threadIdx.x, lane = tid & 63, w = tid >> 6;
  ((floatx4*)bh_s)[tid] = ((const floatx4*)bh)[tid];
  ((floatx4*)wo_s)[tid] = ((const floatx4*)Wo)[tid];
  __syncthreads();
  int n15 = lane & 15, q = lane >> 4;
  int rbase = (blockIdx.x * 4 + w) * 16;
  int ru = rbase + n15;
  int nd = rules[ru < N_RULES ? ru : N_RULES - 1];
  bf16x8 b0h = *(const bf16x8*)&hi[nd * 64 + q * 8];
  bf16x8 b1h = *(const bf16x8*)&hi[nd * 64 + 32 + q * 8];
  bf16x8 b0l = *(const bf16x8*)&lo[nd * 64 + q * 8];
  bf16x8 b1l = *(const bf16x8*)&lo[nd * 64 + 32 + q * 8];
  float acc = 0.f;
  #pragma unroll 4
  for (int jt = 0; jt < 64; ++jt) {
    const unsigned short* fh = WhFhi + (jt * 2) * 512 + lane * 8;
    const unsigned short* fl = WhFlo + (jt * 2) * 512 + lane * 8;
    bf16x8 a0h = *(const bf16x8*)fh;
    bf16x8 a1h = *(const bf16x8*)(fh + 512);
    bf16x8 a0l = *(const bf16x8*)fl;
    bf16x8 a1l = *(const bf16x8*)(fl + 512);
    floatx4 d4 = {0.f, 0.f, 0.f, 0.f};
    d4 = __builtin_amdgcn_mfma_f32_16x16x32_bf16(a0h, b0h, d4, 0, 0, 0);
    d4 = __builtin_amdgcn_mfma_f32_16x16x32_bf16(a1h, b1h, d4, 0, 0, 0);
    d4 = __builtin_amdgcn_mfma_f32_16x16x32_bf16(a0h, b0l, d4, 0, 0, 0);
    d4 = __builtin_amdgcn_mfma_f32_16x16x32_bf16(a1h, b1l, d4, 0, 0, 0);
    d4 = __builtin_amdgcn_mfma_f32_16x16x32_bf16(a0l, b0h, d4, 0, 0, 0);
    d4 = __builtin_amdgcn_mfma_f32_16x16x32_bf16(a1l, b1h, d4, 0, 0, 0);
    floatx4 bh4 = *(const floatx4*)&bh_s[jt * 16 + q * 4];
    floatx4 wo4 = *(const floatx4*)&wo_s[jt * 16 + q * 4];
    #pragma unroll
    for (int i = 0; i < 4; ++i)
      acc += fmaxf(d4[i] + bh4[i], 0.f) * wo4[i];
  }
  acc += __shfl_down(acc, 32);     // fold q2,q3 into q0,q1
  acc += __shfl_down(acc, 16);     // fold q1 into q0
  if (lane < 16 && rbase + lane < N_RULES) out[rbase + lane] = acc;
}

// ---------------- launch ----------------
extern "C" void kernel_launch(void* const* d_in, const int* in_sizes, int n_in,
                              void* d_out, int out_size, void* d_ws, size_t ws_size,
                              hipStream_t stream) {
  const int* nodes = (const int*)d_in[0];
  const int* sources = (const int*)d_in[1];
  const int* targets = (const int*)d_in[2];
  const int* rules = (const int*)d_in[3];
  const float* emb = (const float*)d_in[4];
  const float* W = (const float*)d_in[5];
  const float* b = (const float*)d_in[6];
  const float* gamma = (const float*)d_in[7];
  const float* beta = (const float*)d_in[8];
  const float* rmean = (const float*)d_in[9];
  const float* rvar = (const float*)d_in[10];
  const float* Wh = (const float*)d_in[11];
  const float* bh = (const float*)d_in[12];
  const float* Wo = (const float*)d_in[13];
  float* out = (float*)d_out;

  if (ws_size < 95100000u) return;  // need ~95.1 MB scratch

  char* ws = (char*)d_ws;
  unsigned short* hi_a = (unsigned short*)(ws + 0);          // 25.6 MB
  unsigned short* hi_b = (unsigned short*)(ws + 25600000);   // 25.6 MB
  unsigned short* lo   = (unsigned short*)(ws + 51200000);   // 25.6 MB
  int* deg_out  = (int*)(ws + 76800000);                     // 800 KB
  int* deg_back = (int*)(ws + 77600000);                     // 800 KB
  int* rank_out = (int*)(ws + 78400000);                     // 3.2 MB
  int* rank_back= (int*)(ws + 81600000);                     // 3.2 MB
  int* rp_out   = (int*)(ws + 84800000);                     // RP_STRIDE ints
  int* rp_back  = (int*)(ws + 85600256);
  int* ci_out   = (int*)(ws + 86400512);                     // 3.2 MB
  int* ci_back  = (int*)(ws + 89600512);                     // 3.2 MB
  int* part     = (int*)(ws + 92800512);                     // 1568 B
  unsigned short* WpF   = (unsigned short*)(ws + 92802080);  // 384 KB (16B aligned)
  float* bp             = (float*)(ws + 93195296);           // 12 KB
  unsigned short* WhFhi = (unsigned short*)(ws + 93207584);  // 128 KB
  unsigned short* WhFlo = (unsigned short*)(ws + 93338656);  // 128 KB -> ends 93,469,728

  // zero deg_out/deg_back (contiguous 1.6 MB)
  (void)hipMemsetAsync(deg_out, 0, 1600000u, stream);

  k_hist<<<3125, 256, 0, stream>>>(sources, targets, deg_out, deg_back,
                                   rank_out, rank_back);
  k_scanA<<<dim3(SCAN_NB, 2), 256, 0, stream>>>(deg_out, part);
  k_scanB<<<dim3(1, 2), 256, 0, stream>>>(part, rp_out);
  k_scanC<<<dim3(SCAN_NB, 2), 256, 0, stream>>>(deg_out, part, rp_out);
  k_fill<<<3125, 256, 0, stream>>>(sources, targets, rp_out, rp_back,
                                   rank_out, rank_back, ci_out, ci_back);
  k_prep<<<dim3(2, NLAYERS), 64, 0, stream>>>(W, b, gamma, beta, rmean, rvar, WpF, bp);
  k_prep2<<<64, 64, 0, stream>>>(Wh, WhFhi, WhFlo);
  k_embed<<<50000, 256, 0, stream>>>(nodes, emb, hi_a, lo);

  const unsigned short* hin = hi_a;
  unsigned short* hout = hi_b;
  for (int l = 0; l < NLAYERS; ++l) {
    k_layer<<<3125, 256, 0, stream>>>(hin, hout, lo,
                                      rp_out, ci_out, rp_back, ci_back,
                                      WpF + (size_t)l * 8192, bp + (size_t)l * 128);
    const unsigned short* tmp = hin; hin = hout; hout = (unsigned short*)tmp;
  }
  k_final<<<782, 256, 0, stream>>>(hin, lo, rules, WhFhi, WhFlo, bh, Wo, out);
}

// Round 4
// 1499.670 us; speedup vs baseline: 1.2626x; 1.2152x over previous
//
#include <hip/hip_runtime.h>

#define N_NODES 200000
#define N_EDGES 800000
#define N_RULES 50000
#define NLAYERS 24
#define SCAN_NB 196        // ceil(200000/1024)
#define RP_STRIDE 200064   // ints per rp array (padded)

typedef short bf16x8 __attribute__((ext_vector_type(8)));
typedef float floatx4 __attribute__((ext_vector_type(4)));

__device__ __forceinline__ unsigned short f2bf(float f) {
  unsigned int b = __float_as_uint(f);
  b += 0x7FFFu + ((b >> 16) & 1u);          // round-to-nearest-even
  return (unsigned short)(b >> 16);
}
__device__ __forceinline__ float bf2f(unsigned short u) {
  return __uint_as_float(((unsigned int)u) << 16);
}

// ---------------- CSR build (unpadded; rank captured in hist) ----------------

__global__ void k_hist(const int* __restrict__ src, const int* __restrict__ tgt,
                       int* __restrict__ deg_out, int* __restrict__ deg_back,
                       int* __restrict__ rank_out, int* __restrict__ rank_back) {
  int e = blockIdx.x * 256 + threadIdx.x;   // E = 3125*256 exact
  rank_out[e]  = atomicAdd(&deg_out[tgt[e]], 1);   // rank = old count
  rank_back[e] = atomicAdd(&deg_back[src[e]], 1);
}

__global__ void k_scanA(const int* __restrict__ deg, int* __restrict__ part) {
  int y = blockIdx.y;
  const int* d = deg + y * N_NODES;
  __shared__ int sh[256];
  int t = threadIdx.x;
  int base = blockIdx.x * 1024 + t * 4;
  int s = 0;
  #pragma unroll
  for (int k = 0; k < 4; ++k) { int i = base + k; if (i < N_NODES) s += d[i]; }
  sh[t] = s; __syncthreads();
  for (int off = 128; off > 0; off >>= 1) { if (t < off) sh[t] += sh[t + off]; __syncthreads(); }
  if (t == 0) part[y * SCAN_NB + blockIdx.x] = sh[0];
}

__global__ void k_scanB(int* __restrict__ part, int* __restrict__ rp) {
  int y = blockIdx.y;
  __shared__ int buf[256];
  int t = threadIdx.x;
  int v = (t < SCAN_NB) ? part[y * SCAN_NB + t] : 0;
  buf[t] = v; __syncthreads();
  for (int off = 1; off < 256; off <<= 1) {
    int x = (t >= off) ? buf[t - off] : 0;
    __syncthreads();
    buf[t] += x;
    __syncthreads();
  }
  if (t < SCAN_NB) part[y * SCAN_NB + t] = buf[t] - v;   // exclusive
  if (t == 0) rp[y * RP_STRIDE + N_NODES] = N_EDGES;
}

__global__ void k_scanC(const int* __restrict__ deg, const int* __restrict__ part,
                        int* __restrict__ rp) {
  int y = blockIdx.y;
  const int* d = deg + y * N_NODES;
  int* r = rp + y * RP_STRIDE;
  __shared__ int buf[256];
  int t = threadIdx.x;
  int base = blockIdx.x * 1024 + t * 4;
  int dv[4]; int s = 0;
  #pragma unroll
  for (int k = 0; k < 4; ++k) { int i = base + k; dv[k] = (i < N_NODES) ? d[i] : 0; s += dv[k]; }
  buf[t] = s; __syncthreads();
  int sv = s;
  for (int off = 1; off < 256; off <<= 1) {
    int x = (t >= off) ? buf[t - off] : 0;
    __syncthreads();
    buf[t] += x;
    __syncthreads();
  }
  int e = part[y * SCAN_NB + blockIdx.x] + buf[t] - sv;
  #pragma unroll
  for (int k = 0; k < 4; ++k) { int i = base + k; if (i < N_NODES) r[i] = e; e += dv[k]; }
}

// atomic-free fill: slot = rp[node] + rank[e]
__global__ void k_fill(const int* __restrict__ src, const int* __restrict__ tgt,
                       const int* __restrict__ rp_out, const int* __restrict__ rp_back,
                       const int* __restrict__ rank_out, const int* __restrict__ rank_back,
                       int* __restrict__ ci_out, int* __restrict__ ci_back) {
  int e = blockIdx.x * 256 + threadIdx.x;
  int s = src[e], t = tgt[e];
  ci_out[rp_out[t] + rank_out[e]] = s;
  ci_back[rp_back[s] + rank_back[e]] = t;
}

// ---------------- BN-folded weight prep (bf16 MFMA A-fragments) ----------------
__global__ void k_prep(const float* __restrict__ W, const float* __restrict__ b,
                       const float* __restrict__ gamma, const float* __restrict__ beta,
                       const float* __restrict__ rmean, const float* __restrict__ rvar,
                       unsigned short* __restrict__ WpF, float* __restrict__ bp) {
  int d = blockIdx.x, l = blockIdx.y, lane = threadIdx.x;
  int ld = l * 2 + d;
  __shared__ float s_s[64], t_s[64];
  float s = gamma[ld * 64 + lane] * rsqrtf(rvar[ld * 64 + lane] + 1e-5f);
  s_s[lane] = s;
  t_s[lane] = beta[ld * 64 + lane] - rmean[ld * 64 + lane] * s;
  __syncthreads();
  float bias = b[ld * 64 + lane];
  for (int j = 0; j < 64; ++j) bias += W[(ld * 64 + lane) * 64 + j] * t_s[j];
  bp[ld * 64 + lane] = bias;
  #pragma unroll
  for (int f = 0; f < 8; ++f) {
    int ct = f >> 1, kh = f & 1;
    int row = ct * 16 + (lane & 15);
    #pragma unroll
    for (int jj = 0; jj < 8; ++jj) {
      int k = kh * 32 + (lane >> 4) * 8 + jj;
      float val = W[(ld * 64 + row) * 64 + k] * s_s[k];
      WpF[(ld * 8 + f) * 512 + lane * 8 + jj] = f2bf(val);
    }
  }
}

// ---------------- Wh prep: split bf16 hi/lo MFMA A-fragments ----------------
__global__ void k_prep2(const float* __restrict__ Wh,
                        unsigned short* __restrict__ WhFhi,
                        unsigned short* __restrict__ WhFlo) {
  int jt = blockIdx.x, lane = threadIdx.x;
  #pragma unroll
  for (int kh = 0; kh < 2; ++kh) {
    #pragma unroll
    for (int jj = 0; jj < 8; ++jj) {
      int j = jt * 16 + (lane & 15);
      int k = kh * 32 + (lane >> 4) * 8 + jj;
      float wv = Wh[j * 64 + k];
      unsigned short hi = f2bf(wv);
      WhFhi[(jt * 2 + kh) * 512 + lane * 8 + jj] = hi;
      WhFlo[(jt * 2 + kh) * 512 + lane * 8 + jj] = f2bf(wv - bf2f(hi));
    }
  }
}

// ---------------- embedding gather (bf16 hi/lo master) ----------------
__global__ void k_embed(const int* __restrict__ nodes, const float* __restrict__ emb,
                        unsigned short* __restrict__ hi_a,
                        unsigned short* __restrict__ lo) {
  int gid = blockIdx.x * 256 + threadIdx.x;     // N*64 = 50000*256 exact
  int i = gid >> 6, c = gid & 63;
  float v = emb[nodes[i] * 64 + c];
  unsigned short h = f2bf(v);
  hi_a[gid] = h;
  lo[gid] = f2bf(v - bf2f(h));
}

// ---------------- fused layer (round-13 structure) --------------------------
// round-12 occupancy + coalesced epilogue, plus CROSS-DIRECTION interleaved
// gather: per group iteration, dir0's 16 gathers AND dir1's 16 gathers are
// issued back-to-back (32 independent loads in flight), then dir0 accumulates
// (its waitcnt leaves dir1's loads outstanding), then dir1 accumulates.
// Two independent accumulator states make the overlap structural dataflow,
// not a scheduler hint. __launch_bounds__(256,6) (<=~85 VGPR) gives the
// register budget for 32 values in flight.
__global__ __launch_bounds__(256, 6) void k_layer(
    const unsigned short* __restrict__ hi_in,      // gather source + master hi
    unsigned short* __restrict__ hi_out,
    unsigned short* __restrict__ lo,               // master lo (in-place)
    const int* __restrict__ rp0, const int* __restrict__ ci0,
    const int* __restrict__ rp1, const int* __restrict__ ci1,
    const unsigned short* __restrict__ WfL, const float* __restrict__ bpL) {
  __shared__ __align__(16) unsigned short m_s[4][2][16 * 72];  // [warp][dir], bf16, pitch 72
  __shared__ float bp_s[128];
  int tid = threadIdx.x, lane = tid & 63, w = tid >> 6;
  if (tid < 128) bp_s[tid] = bpL[tid];
  __syncthreads();
  int base = (blockIdx.x * 4 + w) * 16;
  int n15 = lane & 15, q = lane >> 4;

  // rp for BOTH dirs into registers; first two ci blocks of BOTH dirs in flight
  int rpv0 = (lane < 17) ? rp0[base + lane] : 0;
  int rpv1 = (lane < 17) ? rp1[base + lane] : 0;
  int rs0 = __builtin_amdgcn_readlane(rpv0, 0);
  int re0 = __builtin_amdgcn_readlane(rpv0, 16);
  int rs1 = __builtin_amdgcn_readlane(rpv1, 0);
  int re1 = __builtin_amdgcn_readlane(rpv1, 16);
  int nb0 = re0 - rs0, nb1 = re1 - rs1;

  int cv0  = (lane < nb0)      ? ci0[rs0 + lane]      : 0;
  int cv1  = (lane < nb1)      ? ci1[rs1 + lane]      : 0;
  int cv0n = (64 + lane < nb0) ? ci0[rs0 + 64 + lane] : 0;
  int cv1n = (64 + lane < nb1) ? ci1[rs1 + 64 + lane] : 0;

  int cur0 = 0, cs0 = rs0, ce0 = __builtin_amdgcn_readlane(rpv0, 1);
  int cur1 = 0, cs1 = rs1, ce1 = __builtin_amdgcn_readlane(rpv1, 1);
  float a0 = 0.f, a1 = 0.f;

  int g0max = (nb0 + 15) >> 4, g1max = (nb1 + 15) >> 4;
  int gmax = g0max > g1max ? g0max : g1max;

  for (int g = 0; g < gmax; ++g) {
    int off = g << 4;
    int boff = off & 63;
    if (g && boff == 0) {                      // 64-block rollover (every 4 groups)
      cv0 = cv0n; cv1 = cv1n;
      cv0n = (off + 64 + lane < nb0) ? ci0[rs0 + off + 64 + lane] : 0;
      cv1n = (off + 64 + lane < nb1) ? ci1[rs1 + off + 64 + lane] : 0;
    }
    bool do0 = off < nb0, do1 = off < nb1;
    float v0[16], v1[16];
    if (do0) {                                 // issue dir0 gathers (16 in flight)
      #pragma unroll
      for (int u = 0; u < 16; ++u) {
        int sn = __builtin_amdgcn_readlane(cv0, boff + u);  // OOB lanes hold 0 -> safe row
        v0[u] = bf2f(hi_in[sn * 64 + lane]);
      }
    }
    if (do1) {                                 // issue dir1 gathers (now 32 in flight)
      #pragma unroll
      for (int u = 0; u < 16; ++u) {
        int sn = __builtin_amdgcn_readlane(cv1, boff + u);
        v1[u] = bf2f(hi_in[sn * 64 + lane]);
      }
    }
    if (do0) {                                 // accumulate dir0 (dir1 loads in flight)
      int jb = rs0 + off;
      #pragma unroll
      for (int u = 0; u < 16; ++u) {
        int j = jb + u;
        if (j < re0) {
          while (j >= ce0) {                   // flush node cur0
            int deg = ce0 - cs0;
            float invc = deg > 0 ? __builtin_amdgcn_rcpf((float)deg) : 0.f;
            m_s[w][0][cur0 * 72 + lane] = f2bf(a0 * invc);
            a0 = 0.f; cur0++; cs0 = ce0;
            ce0 = __builtin_amdgcn_readlane(rpv0, cur0 + 1);
          }
          a0 += v0[u];
        }
      }
    }
    if (do1) {                                 // accumulate dir1
      int jb = rs1 + off;
      #pragma unroll
      for (int u = 0; u < 16; ++u) {
        int j = jb + u;
        if (j < re1) {
          while (j >= ce1) {                   // flush node cur1
            int deg = ce1 - cs1;
            float invc = deg > 0 ? __builtin_amdgcn_rcpf((float)deg) : 0.f;
            m_s[w][1][cur1 * 72 + lane] = f2bf(a1 * invc);
            a1 = 0.f; cur1++; cs1 = ce1;
            ce1 = __builtin_amdgcn_readlane(rpv1, cur1 + 1);
          }
          a1 += v1[u];
        }
      }
    }
  }
  #pragma unroll 1
  while (cur0 < 16) {                          // trailing flush dir0
    int deg = ce0 - cs0;
    float invc = deg > 0 ? __builtin_amdgcn_rcpf((float)deg) : 0.f;
    m_s[w][0][cur0 * 72 + lane] = f2bf(a0 * invc);
    a0 = 0.f; cs0 = ce0; cur0++;
    if (cur0 < 16) ce0 = __builtin_amdgcn_readlane(rpv0, cur0 + 1);
  }
  #pragma unroll 1
  while (cur1 < 16) {                          // trailing flush dir1
    int deg = ce1 - cs1;
    float invc = deg > 0 ? __builtin_amdgcn_rcpf((float)deg) : 0.f;
    m_s[w][1][cur1 * 72 + lane] = f2bf(a1 * invc);
    a1 = 0.f; cs1 = ce1; cur1++;
    if (cur1 < 16) ce1 = __builtin_amdgcn_readlane(rpv1, cur1 + 1);
  }

  // -------- MFMA both dirs; y into warp-private LDS scratch (reuses m_s) ----
  bf16x8 b0d0 = *(const bf16x8*)&m_s[w][0][n15 * 72 + q * 8];
  bf16x8 b1d0 = *(const bf16x8*)&m_s[w][0][n15 * 72 + 32 + q * 8];
  bf16x8 b0d1 = *(const bf16x8*)&m_s[w][1][n15 * 72 + q * 8];
  bf16x8 b1d1 = *(const bf16x8*)&m_s[w][1][n15 * 72 + 32 + q * 8];
  float* ys = (float*)&m_s[w][0][0];                   // 4352 B <= 4608 B region
  #pragma unroll
  for (int ct = 0; ct < 4; ++ct) {
    const unsigned short* wf0 = WfL + (ct * 2) * 512 + lane * 8;        // d0 frags
    const unsigned short* wf1 = WfL + 4096 + (ct * 2) * 512 + lane * 8; // d1 frags
    floatx4 d40 = {0.f, 0.f, 0.f, 0.f};
    floatx4 d41 = {0.f, 0.f, 0.f, 0.f};
    d40 = __builtin_amdgcn_mfma_f32_16x16x32_bf16(*(const bf16x8*)wf0, b0d0, d40, 0, 0, 0);
    d40 = __builtin_amdgcn_mfma_f32_16x16x32_bf16(*(const bf16x8*)(wf0 + 512), b1d0, d40, 0, 0, 0);
    d41 = __builtin_amdgcn_mfma_f32_16x16x32_bf16(*(const bf16x8*)wf1, b0d1, d41, 0, 0, 0);
    d41 = __builtin_amdgcn_mfma_f32_16x16x32_bf16(*(const bf16x8*)(wf1 + 512), b1d1, d41, 0, 0, 0);
    // D: col = n15 = node, row = ct*16 + q*4 + i = channel
    int c0 = ct * 16 + q * 4;
    floatx4 yv;
    #pragma unroll
    for (int i = 0; i < 4; ++i)
      yv[i] = fmaxf(d40[i] + bp_s[c0 + i], 0.f)
            + fmaxf(d41[i] + bp_s[64 + c0 + i], 0.f);
    *(floatx4*)&ys[n15 * 68 + c0] = yv;                // pitch 68 f32
  }

  // epilogue: row-major coalesced; residual on hi/lo, re-split, store
  #pragma unroll
  for (int r = 0; r < 16; ++r) {
    int gi = (base + r) * 64 + lane;
    float xv = bf2f(hi_in[gi]) + bf2f(lo[gi]) + ys[r * 68 + lane];
    unsigned short h = f2bf(xv);
    hi_out[gi] = h;
    lo[gi] = f2bf(xv - bf2f(h));   // in-place: only this warp touches these rows
  }
}

// ---------------- readout (MFMA; hi/lo split comes free from master format) ----
__global__ __launch_bounds__(256) void k_final(
    const unsigned short* __restrict__ hi, const unsigned short* __restrict__ lo,
    const int* __restrict__ rules,
    const unsigned short* __restrict__ WhFhi, const unsigned short* __restrict__ WhFlo,
    const float* __restrict__ bh, const float* __restrict__ Wo,
    float* __restrict__ out) {
  __shared__ __align__(16) float bh_s[1024], wo_s[1024];
  int tid = threadIdx.x, lane = tid & 63, w = tid >> 6;
  ((floatx4*)bh_s)[tid] = ((const floatx4*)bh)[tid];
  ((floatx4*)wo_s)[tid] = ((const floatx4*)Wo)[tid];
  __syncthreads();
  int n15 = lane & 15, q = lane >> 4;
  int rbase = (blockIdx.x * 4 + w) * 16;
  int ru = rbase + n15;
  int nd = rules[ru < N_RULES ? ru : N_RULES - 1];
  bf16x8 b0h = *(const bf16x8*)&hi[nd * 64 + q * 8];
  bf16x8 b1h = *(const bf16x8*)&hi[nd * 64 + 32 + q * 8];
  bf16x8 b0l = *(const bf16x8*)&lo[nd * 64 + q * 8];
  bf16x8 b1l = *(const bf16x8*)&lo[nd * 64 + 32 + q * 8];
  float acc = 0.f;
  #pragma unroll 4
  for (int jt = 0; jt < 64; ++jt) {
    const unsigned short* fh = WhFhi + (jt * 2) * 512 + lane * 8;
    const unsigned short* fl = WhFlo + (jt * 2) * 512 + lane * 8;
    bf16x8 a0h = *(const bf16x8*)fh;
    bf16x8 a1h = *(const bf16x8*)(fh + 512);
    bf16x8 a0l = *(const bf16x8*)fl;
    bf16x8 a1l = *(const bf16x8*)(fl + 512);
    floatx4 d4 = {0.f, 0.f, 0.f, 0.f};
    d4 = __builtin_amdgcn_mfma_f32_16x16x32_bf16(a0h, b0h, d4, 0, 0, 0);
    d4 = __builtin_amdgcn_mfma_f32_16x16x32_bf16(a1h, b1h, d4, 0, 0, 0);
    d4 = __builtin_amdgcn_mfma_f32_16x16x32_bf16(a0h, b0l, d4, 0, 0, 0);
    d4 = __builtin_amdgcn_mfma_f32_16x16x32_bf16(a1h, b1l, d4, 0, 0, 0);
    d4 = __builtin_amdgcn_mfma_f32_16x16x32_bf16(a0l, b0h, d4, 0, 0, 0);
    d4 = __builtin_amdgcn_mfma_f32_16x16x32_bf16(a1l, b1h, d4, 0, 0, 0);
    floatx4 bh4 = *(const floatx4*)&bh_s[jt * 16 + q * 4];
    floatx4 wo4 = *(const floatx4*)&wo_s[jt * 16 + q * 4];
    #pragma unroll
    for (int i = 0; i < 4; ++i)
      acc += fmaxf(d4[i] + bh4[i], 0.f) * wo4[i];
  }
  acc += __shfl_down(acc, 32);     // fold q2,q3 into q0,q1
  acc += __shfl_down(acc, 16);     // fold q1 into q0
  if (lane < 16 && rbase + lane < N_RULES) out[rbase + lane] = acc;
}

// ---------------- launch ----------------
extern "C" void kernel_launch(void* const* d_in, const int* in_sizes, int n_in,
                              void* d_out, int out_size, void* d_ws, size_t ws_size,
                              hipStream_t stream) {
  const int* nodes = (const int*)d_in[0];
  const int* sources = (const int*)d_in[1];
  const int* targets = (const int*)d_in[2];
  const int* rules = (const int*)d_in[3];
  const float* emb = (const float*)d_in[4];
  const float* W = (const float*)d_in[5];
  const float* b = (const float*)d_in[6];
  const float* gamma = (const float*)d_in[7];
  const float* beta = (const float*)d_in[8];
  const float* rmean = (const float*)d_in[9];
  const float* rvar = (const float*)d_in[10];
  const float* Wh = (const float*)d_in[11];
  const float* bh = (const float*)d_in[12];
  const float* Wo = (const float*)d_in[13];
  float* out = (float*)d_out;

  if (ws_size < 95100000u) return;  // need ~95.1 MB scratch

  char* ws = (char*)d_ws;
  unsigned short* hi_a = (unsigned short*)(ws + 0);          // 25.6 MB
  unsigned short* hi_b = (unsigned short*)(ws + 25600000);   // 25.6 MB
  unsigned short* lo   = (unsigned short*)(ws + 51200000);   // 25.6 MB
  int* deg_out  = (int*)(ws + 76800000);                     // 800 KB
  int* deg_back = (int*)(ws + 77600000);                     // 800 KB
  int* rank_out = (int*)(ws + 78400000);                     // 3.2 MB
  int* rank_back= (int*)(ws + 81600000);                     // 3.2 MB
  int* rp_out   = (int*)(ws + 84800000);                     // RP_STRIDE ints
  int* rp_back  = (int*)(ws + 85600256);
  int* ci_out   = (int*)(ws + 86400512);                     // 3.2 MB
  int* ci_back  = (int*)(ws + 89600512);                     // 3.2 MB
  int* part     = (int*)(ws + 92800512);                     // 1568 B
  unsigned short* WpF   = (unsigned short*)(ws + 92802080);  // 384 KB (16B aligned)
  float* bp             = (float*)(ws + 93195296);           // 12 KB
  unsigned short* WhFhi = (unsigned short*)(ws + 93207584);  // 128 KB
  unsigned short* WhFlo = (unsigned short*)(ws + 93338656);  // 128 KB -> ends 93,469,728

  // zero deg_out/deg_back (contiguous 1.6 MB)
  (void)hipMemsetAsync(deg_out, 0, 1600000u, stream);

  k_hist<<<3125, 256, 0, stream>>>(sources, targets, deg_out, deg_back,
                                   rank_out, rank_back);
  k_scanA<<<dim3(SCAN_NB, 2), 256, 0, stream>>>(deg_out, part);
  k_scanB<<<dim3(1, 2), 256, 0, stream>>>(part, rp_out);
  k_scanC<<<dim3(SCAN_NB, 2), 256, 0, stream>>>(deg_out, part, rp_out);
  k_fill<<<3125, 256, 0, stream>>>(sources, targets, rp_out, rp_back,
                                   rank_out, rank_back, ci_out, ci_back);
  k_prep<<<dim3(2, NLAYERS), 64, 0, stream>>>(W, b, gamma, beta, rmean, rvar, WpF, bp);
  k_prep2<<<64, 64, 0, stream>>>(Wh, WhFhi, WhFlo);
  k_embed<<<50000, 256, 0, stream>>>(nodes, emb, hi_a, lo);

  const unsigned short* hin = hi_a;
  unsigned short* hout = hi_b;
  for (int l = 0; l < NLAYERS; ++l) {
    k_layer<<<3125, 256, 0, stream>>>(hin, hout, lo,
                                      rp_out, ci_out, rp_back, ci_back,
                                      WpF + (size_t)l * 8192, bp + (size_t)l * 128);
    const unsigned short* tmp = hin; hin = hout; hout = (unsigned short*)tmp;
  }
  k_final<<<782, 256, 0, stream>>>(hin, lo, rules, WhFhi, WhFlo, bh, Wo, out);
}